// Round 4
// baseline (67782.220 us; speedup 1.0000x reference)
//
#include <hip/hip_runtime.h>
#include <hip/hip_cooperative_groups.h>
#include <math.h>

namespace cg = cooperative_groups;

typedef unsigned short u16;
typedef unsigned int   u32;
typedef __attribute__((ext_vector_type(4))) float f32x4;
typedef __attribute__((ext_vector_type(8))) short short8;

#define B_ 32
#define S_ 256
#define E_ 256
#define H_ 512
#define L_ 1024

// ---- workspace layout (float offsets), total 10,537,024 f = 42.15 MB ----
#define OFF_HEB   0           // bf16 h_e: 16,777,216 u16 = 8,388,608 f  (LIVE whole kernel)
#define OFF_WCAT  8388608     // bf16 [2048][1280] = 1,310,720 f
#define OFF_WST   9699328     // bf16 W_s^T [512][512] = 131,072 f
#define OFF_PG    9830400     // 2*32*2048 f = 131,072
#define OFF_PSE   9961472     // 16*32*512 f = 262,144
#define OFF_PA    10223616    // 32*16*516 f = 264,192
#define OFF_CNT   10487808    // 32 ints (+pad to 64 f)
#define OFF_HB    10487872    // 2*32*512 u16 = 16,384 f (hi/lo bf16 of h)
#define OFF_ATTB  10504256    // 16,384 f (hi/lo bf16 of att)
#define OFF_C     10520640    // 16,384 f fp32 cell state

__device__ inline u16 f2bf(float x) {
    u32 u = __float_as_uint(x);
    u += 0x7fffu + ((u >> 16) & 1u);
    return (u16)(u >> 16);
}
__device__ inline float bfv(u16 h) { return __uint_as_float((u32)h << 16); }
__device__ inline float bflo(u32 q) { return __uint_as_float(q << 16); }
__device__ inline float bfhi(u32 q) { return __uint_as_float(q & 0xffff0000u); }

__device__ inline void cvt8(const float* __restrict__ src, short8& hi, short8& lo) {
    union { short8 s; u16 h[8]; } H, Lo;
    #pragma unroll
    for (int i = 0; i < 8; ++i) {
        float v = src[i];
        u16 hh = f2bf(v);
        H.h[i] = hh;
        Lo.h[i] = f2bf(v - bfv(hh));
    }
    hi = H.s; lo = Lo.s;
}

// ---------------- pre: wcat bf16 [2048][1280] = [Wih | Whh]; wst bf16 = Ws^T ----------------
__global__ void k_cvt(const float* __restrict__ Wih, const float* __restrict__ Whh,
                      const float* __restrict__ Ws,
                      u16* __restrict__ wcat, u16* __restrict__ wst) {
    int idx = blockIdx.x * 256 + threadIdx.x;
    if (idx < 655360) {
        int e4 = idx * 4;
        int r = e4 / 1280, cc = e4 % 1280;
        float4 v;
        if (cc < 768) v = *(const float4*)(Wih + (size_t)r * 768 + cc);
        else          v = *(const float4*)(Whh + (size_t)r * 512 + (cc - 768));
        ushort4 o;
        o.x = f2bf(v.x); o.y = f2bf(v.y); o.z = f2bf(v.z); o.w = f2bf(v.w);
        *(ushort4*)(wcat + e4) = o;
    } else if (idx < 655360 + 262144) {
        int i2 = idx - 655360;
        int j = i2 >> 9, r = i2 & 511;
        wst[i2] = f2bf(Ws[(size_t)r * 512 + j]);
    }
}

// ---------------- h_e = encoder_h @ W_h.T + b_h  (bf16 out) — proven R2 kernel ----------------
__global__ __launch_bounds__(256) void k_he(const float* __restrict__ A,
                                            const float* __restrict__ W,
                                            const float* __restrict__ bias,
                                            u16* __restrict__ C) {
    __shared__ float As[64][36];
    __shared__ float Bs[64][37];
    const int m0 = blockIdx.y * 64;
    const int n0 = blockIdx.x * 64;
    const int tid = threadIdx.x;
    const int tx = tid & 15, ty = tid >> 4;
    float acc[4][4] = {};
    for (int kk = 0; kk < 512; kk += 32) {
        #pragma unroll
        for (int i = 0; i < 2; ++i) {
            int idx = tid + i * 256;
            int r = idx >> 3, c4 = (idx & 7) << 2;
            float4 va = *(const float4*)(A + (size_t)(m0 + r) * 512 + kk + c4);
            *(float4*)&As[r][c4] = va;
            float4 vb = *(const float4*)(W + (size_t)(n0 + r) * 512 + kk + c4);
            Bs[r][c4 + 0] = vb.x; Bs[r][c4 + 1] = vb.y;
            Bs[r][c4 + 2] = vb.z; Bs[r][c4 + 3] = vb.w;
        }
        __syncthreads();
        #pragma unroll
        for (int k2 = 0; k2 < 32; ++k2) {
            float a[4], b[4];
            #pragma unroll
            for (int i = 0; i < 4; ++i) a[i] = As[ty * 4 + i][k2];
            #pragma unroll
            for (int j = 0; j < 4; ++j) b[j] = Bs[tx * 4 + j][k2];
            #pragma unroll
            for (int i = 0; i < 4; ++i)
                #pragma unroll
                for (int j = 0; j < 4; ++j) acc[i][j] += a[i] * b[j];
        }
        __syncthreads();
    }
    float bj[4];
    #pragma unroll
    for (int j = 0; j < 4; ++j) bj[j] = bias[n0 + tx * 4 + j];
    #pragma unroll
    for (int i = 0; i < 4; ++i) {
        ushort4 r4;
        r4.x = f2bf(acc[i][0] + bj[0]); r4.y = f2bf(acc[i][1] + bj[1]);
        r4.z = f2bf(acc[i][2] + bj[2]); r4.w = f2bf(acc[i][3] + bj[3]);
        *(ushort4*)(C + (size_t)(m0 + ty * 4 + i) * 512 + n0 + tx * 4) = r4;
    }
}

// ---------------- shared phase implementations ----------------
struct P {
    const float* y;
    const u16*   heb;
    const u16*   wcat;
    const u16*   wst;
    const float* bih;
    const float* bhh;
    const float* bs;
    float*       pg;
    float*       pse;
    float*       pa;
    int*         cnt;
    u16*         hb;
    u16*         attb;
    float*       c;
    float*       out_h;
    float*       out_att;
};

__device__ void phase0(const P& p, int bid, int t) {
    int i = bid * 256 + t;
    if (i < 16384)        ((float*)p.hb)[i] = 0.f;
    else if (i < 32768)   ((float*)p.attb)[i - 16384] = 0.f;
    else if (i < 49152)   p.c[i - 32768] = 0.f;
    if (i < 32) p.cnt[i] = 0;
}

// gates: pg[ks][b][row] via MFMA. 64 active blocks: (m4 row-tile of 64) x (ks in 2).
__device__ void phaseA(const P& p, int tstep, int bid, int t) {
    if (bid >= 64) return;
    const int wv = t >> 6, lane = t & 63;
    const int m4 = bid >> 1, ks = bid & 1;
    const int r0 = m4 * 64 + wv * 16;
    const int row = lane & 15, q = lane >> 4;
    const int rb = r0 + row, ksl = q * 8;
    f32x4 acc0 = {0.f, 0.f, 0.f, 0.f}, acc1 = {0.f, 0.f, 0.f, 0.f};
    const int kbeg = ks * 640;
    #pragma unroll 4
    for (int kc = kbeg; kc < kbeg + 640; kc += 32) {
        union { uint4 u; short8 s; } A, B0h, B0l, B1h, B1l;
        A.u = *(const uint4*)(p.wcat + (size_t)rb * 1280 + kc + ksl);
        if (kc < 256) {
            cvt8(p.y + (size_t)row * 65536 + (size_t)tstep * 256 + kc + ksl, B0h.s, B0l.s);
            cvt8(p.y + (size_t)(16 + row) * 65536 + (size_t)tstep * 256 + kc + ksl, B1h.s, B1l.s);
        } else if (kc < 768) {
            size_t o0 = (size_t)row * 512 + (kc - 256) + ksl;
            size_t o1 = (size_t)(16 + row) * 512 + (kc - 256) + ksl;
            B0h.u = *(const uint4*)(p.attb + o0);
            B0l.u = *(const uint4*)(p.attb + 16384 + o0);
            B1h.u = *(const uint4*)(p.attb + o1);
            B1l.u = *(const uint4*)(p.attb + 16384 + o1);
        } else {
            size_t o0 = (size_t)row * 512 + (kc - 768) + ksl;
            size_t o1 = (size_t)(16 + row) * 512 + (kc - 768) + ksl;
            B0h.u = *(const uint4*)(p.hb + o0);
            B0l.u = *(const uint4*)(p.hb + 16384 + o0);
            B1h.u = *(const uint4*)(p.hb + o1);
            B1l.u = *(const uint4*)(p.hb + 16384 + o1);
        }
        acc0 = __builtin_amdgcn_mfma_f32_16x16x32_bf16(A.s, B0h.s, acc0, 0, 0, 0);
        acc0 = __builtin_amdgcn_mfma_f32_16x16x32_bf16(A.s, B0l.s, acc0, 0, 0, 0);
        acc1 = __builtin_amdgcn_mfma_f32_16x16x32_bf16(A.s, B1h.s, acc1, 0, 0, 0);
        acc1 = __builtin_amdgcn_mfma_f32_16x16x32_bf16(A.s, B1l.s, acc1, 0, 0, 0);
    }
    // D layout: col = lane&15 (batch), rows = q*4 + i
    float4 s0, s1;
    s0.x = acc0[0]; s0.y = acc0[1]; s0.z = acc0[2]; s0.w = acc0[3];
    s1.x = acc1[0]; s1.y = acc1[1]; s1.z = acc1[2]; s1.w = acc1[3];
    *(float4*)(p.pg + ((size_t)ks * 32 + row) * 2048 + r0 + q * 4) = s0;
    *(float4*)(p.pg + ((size_t)ks * 32 + 16 + row) * 2048 + r0 + q * 4) = s1;
}

// reduce gates + LSTM pointwise + s_e partials. 128 active blocks.
__device__ void phaseB(const P& p, int tstep, int bid, int t) {
    if (bid >= 128) return;
    __shared__ float hloc[32][4];
    const int dtl = bid >> 3;   // d-tile (32 d)
    const int bgl = bid & 7;    // 4 batches
    if (t < 128) {
        const int d = dtl * 32 + (t & 31);
        const int b = bgl * 4 + (t >> 5);
        float g0 = p.bih[d]        + p.bhh[d];
        float g1 = p.bih[512 + d]  + p.bhh[512 + d];
        float g2 = p.bih[1024 + d] + p.bhh[1024 + d];
        float g3 = p.bih[1536 + d] + p.bhh[1536 + d];
        #pragma unroll
        for (int k = 0; k < 2; ++k) {
            const float* pp = p.pg + (size_t)k * 65536 + (size_t)b * 2048 + d;
            g0 += pp[0]; g1 += pp[512]; g2 += pp[1024]; g3 += pp[1536];
        }
        float si = 1.f / (1.f + __expf(-g0));
        float sf = 1.f / (1.f + __expf(-g1));
        float so = 1.f / (1.f + __expf(-g3));
        float cc = sf * p.c[b * 512 + d] + si * tanhf(g2);
        float hv = so * tanhf(cc);
        p.c[b * 512 + d] = cc;
        p.out_h[(size_t)b * (S_ * H_) + (size_t)tstep * H_ + d] = hv;
        u16 hi = f2bf(hv);
        p.hb[(size_t)b * 512 + d] = hi;
        p.hb[16384 + (size_t)b * 512 + d] = f2bf(hv - bfv(hi));
        hloc[t & 31][t >> 5] = hv;
    }
    __syncthreads();
    // pse[dtl][b][r] = sum_{j in dtl} Ws[r][j] * h[b][j]
    float a0[4] = {0.f, 0.f, 0.f, 0.f}, a1[4] = {0.f, 0.f, 0.f, 0.f};
    #pragma unroll 4
    for (int j = 0; j < 32; ++j) {
        const u16* wr = p.wst + (size_t)(dtl * 32 + j) * 512 + t;
        float w0 = bfv(wr[0]);
        float w1 = bfv(wr[256]);
        float h0 = hloc[j][0], h1 = hloc[j][1], h2 = hloc[j][2], h3 = hloc[j][3];
        a0[0] += w0 * h0; a0[1] += w0 * h1; a0[2] += w0 * h2; a0[3] += w0 * h3;
        a1[0] += w1 * h0; a1[1] += w1 * h1; a1[2] += w1 * h2; a1[3] += w1 * h3;
    }
    #pragma unroll
    for (int bb = 0; bb < 4; ++bb) {
        const int b = bgl * 4 + bb;
        p.pse[(size_t)dtl * 16384 + (size_t)b * 512 + t]       = a0[bb];
        p.pse[(size_t)dtl * 16384 + (size_t)b * 512 + t + 256] = a1[bb];
    }
}

// attention: e + chunk softmax + ctx partials + last-block combine. 512 blocks.
__device__ void phaseC(const P& p, int tstep, int bid, int t) {
    __shared__ float se[512];
    __shared__ float part[64][5];
    __shared__ float pl[64];
    __shared__ float sm16[16], sz16[16], swt[16];
    __shared__ float mzm, mzz, szt;
    __shared__ int   flag;
    const int b = bid >> 4, ch = bid & 15;
    const int l0 = ch * 64;
    #pragma unroll
    for (int i = 0; i < 2; ++i) {
        int r = t + i * 256;
        float v = p.bs[r];
        #pragma unroll
        for (int dd = 0; dd < 16; ++dd)
            v += p.pse[(size_t)dd * 16384 + (size_t)b * 512 + r];
        se[r] = v;
    }
    __syncthreads();
    {   // e_l partials: lane covers (l = t&63, w = t>>6 h-range of 128)
        const int l = t & 63, w = t >> 6;
        const u16* hrow = p.heb + ((size_t)b * L_ + l0 + l) * H_ + w * 128;
        const float* sew = &se[w * 128];
        float dp = 0.f;
        #pragma unroll
        for (int kc = 0; kc < 128; kc += 8) {
            uint4 qq = *(const uint4*)(hrow + kc);
            dp += sew[kc + 0] * bflo(qq.x) + sew[kc + 1] * bfhi(qq.x)
                + sew[kc + 2] * bflo(qq.y) + sew[kc + 3] * bfhi(qq.y)
                + sew[kc + 4] * bflo(qq.z) + sew[kc + 5] * bfhi(qq.z)
                + sew[kc + 6] * bflo(qq.w) + sew[kc + 7] * bfhi(qq.w);
        }
        part[l][w] = dp;
    }
    __syncthreads();
    if (t < 64) {
        float e = part[t][0] + part[t][1] + part[t][2] + part[t][3];
        float m = e;
        #pragma unroll
        for (int off = 1; off < 64; off <<= 1) m = fmaxf(m, __shfl_xor(m, off));
        float pv = __expf(e - m);
        float Z = pv;
        #pragma unroll
        for (int off = 1; off < 64; off <<= 1) Z += __shfl_xor(Z, off);
        pl[t] = pv;
        if (t == 0) { mzm = m; mzz = Z; }
    }
    __syncthreads();
    {   // ctx partials: thread covers 2 h over all 64 l (tile hot in L2)
        float c0 = 0.f, c1 = 0.f;
        const u16* base2 = p.heb + ((size_t)b * L_ + l0) * H_ + t * 2;
        #pragma unroll 8
        for (int j = 0; j < 64; ++j) {
            u32 qq = *(const u32*)(base2 + (size_t)j * 512);
            float pv = pl[j];
            c0 += pv * bflo(qq); c1 += pv * bfhi(qq);
        }
        float* dst = p.pa + ((size_t)b * 16 + ch) * 516;
        dst[2 * t] = c0; dst[2 * t + 1] = c1;
        if (t == 0) { dst[512] = mzm; dst[513] = mzz; }
    }
    __threadfence();
    __syncthreads();
    if (t == 0) {
        int old = atomicAdd(&p.cnt[b], 1);
        flag = (old == 15) ? 1 : 0;
        if (old == 15) p.cnt[b] = 0;
    }
    __syncthreads();
    if (flag) {
        __threadfence();
        if (t < 16) {
            const volatile float* pm = p.pa + ((size_t)b * 16 + t) * 516;
            sm16[t] = pm[512];
            sz16[t] = pm[513];
        }
        __syncthreads();
        if (t == 0) {
            float M = sm16[0];
            #pragma unroll
            for (int i2 = 1; i2 < 16; ++i2) M = fmaxf(M, sm16[i2]);
            float Zt = 0.f;
            #pragma unroll
            for (int i2 = 0; i2 < 16; ++i2) {
                float wv2 = __expf(sm16[i2] - M);
                swt[i2] = wv2;
                Zt += wv2 * sz16[i2];
            }
            szt = Zt;
        }
        __syncthreads();
        const float inv = 1.f / szt;
        float A0 = 0.f, A1 = 0.f;
        #pragma unroll
        for (int i2 = 0; i2 < 16; ++i2) {
            const volatile float* pp = p.pa + ((size_t)b * 16 + i2) * 516 + 2 * t;
            float wv2 = swt[i2];
            A0 += wv2 * pp[0]; A1 += wv2 * pp[1];
        }
        A0 *= inv; A1 *= inv;
        p.out_att[(size_t)b * (S_ * H_) + (size_t)tstep * H_ + 2 * t]     = A0;
        p.out_att[(size_t)b * (S_ * H_) + (size_t)tstep * H_ + 2 * t + 1] = A1;
        u16 h0 = f2bf(A0), h1 = f2bf(A1);
        p.attb[(size_t)b * 512 + 2 * t]     = h0;
        p.attb[(size_t)b * 512 + 2 * t + 1] = h1;
        p.attb[16384 + (size_t)b * 512 + 2 * t]     = f2bf(A0 - bfv(h0));
        p.attb[16384 + (size_t)b * 512 + 2 * t + 1] = f2bf(A1 - bfv(h1));
    }
}

// ---------------- driver 1: persistent cooperative ----------------
__global__ __launch_bounds__(256, 2) void k_steps(P p) {
    cg::grid_group g = cg::this_grid();
    phase0(p, blockIdx.x, threadIdx.x);
    g.sync();
    for (int ts = 0; ts < S_; ++ts) {
        phaseA(p, ts, blockIdx.x, threadIdx.x);
        g.sync();
        phaseB(p, ts, blockIdx.x, threadIdx.x);
        g.sync();
        phaseC(p, ts, blockIdx.x, threadIdx.x);
        g.sync();
    }
}

// ---------------- driver 2: fallback multi-launch (same phases) ----------------
__global__ __launch_bounds__(256) void k_p0(P p) { phase0(p, blockIdx.x, threadIdx.x); }
__global__ __launch_bounds__(256) void k_pA(P p, int ts) { phaseA(p, ts, blockIdx.x, threadIdx.x); }
__global__ __launch_bounds__(256) void k_pB(P p, int ts) { phaseB(p, ts, blockIdx.x, threadIdx.x); }
__global__ __launch_bounds__(256) void k_pC(P p, int ts) { phaseC(p, ts, blockIdx.x, threadIdx.x); }

extern "C" void kernel_launch(void* const* d_in, const int* in_sizes, int n_in,
                              void* d_out, int out_size, void* d_ws, size_t ws_size,
                              hipStream_t stream) {
    const float* y   = (const float*)d_in[0];
    const float* enc = (const float*)d_in[1];
    const float* Wih = (const float*)d_in[2];
    const float* bih = (const float*)d_in[3];
    const float* Whh = (const float*)d_in[4];
    const float* bhh = (const float*)d_in[5];
    const float* Ws_ = (const float*)d_in[6];
    const float* bs  = (const float*)d_in[7];
    const float* Wh  = (const float*)d_in[8];
    const float* bh  = (const float*)d_in[9];

    float* ws = (float*)d_ws;
    u16*   heb  = (u16*)(ws + OFF_HEB);
    u16*   wcat = (u16*)(ws + OFF_WCAT);
    u16*   wst  = (u16*)(ws + OFF_WST);
    float* out_h   = (float*)d_out;
    float* out_att = out_h + (size_t)B_ * S_ * H_;

    k_cvt<<<3584, 256, 0, stream>>>(Wih, Whh, Ws_, wcat, wst);
    k_he<<<dim3(8, 512), 256, 0, stream>>>(enc, Wh, bh, heb);

    P p;
    p.y = y; p.heb = heb; p.wcat = wcat; p.wst = wst;
    p.bih = bih; p.bhh = bhh; p.bs = bs;
    p.pg  = ws + OFF_PG;
    p.pse = ws + OFF_PSE;
    p.pa  = ws + OFF_PA;
    p.cnt = (int*)(ws + OFF_CNT);
    p.hb   = (u16*)(ws + OFF_HB);
    p.attb = (u16*)(ws + OFF_ATTB);
    p.c    = ws + OFF_C;
    p.out_h = out_h; p.out_att = out_att;

    void* args[] = { &p };
    hipError_t err = hipLaunchCooperativeKernel((const void*)k_steps,
                                                dim3(512), dim3(256), args, 0, stream);
    if (err != hipSuccess) {
        (void)hipGetLastError();   // clear sticky error, use fallback path
        k_p0<<<512, 256, 0, stream>>>(p);
        for (int ts = 0; ts < S_; ++ts) {
            k_pA<<<64, 256, 0, stream>>>(p, ts);
            k_pB<<<128, 256, 0, stream>>>(p, ts);
            k_pC<<<512, 256, 0, stream>>>(p, ts);
        }
    }
}

// Round 6
// 35232.355 us; speedup vs baseline: 1.9239x; 1.9239x over previous
//
#include <hip/hip_runtime.h>
#include <hip/hip_cooperative_groups.h>
#include <math.h>

typedef unsigned short u16;
typedef unsigned int   u32;
typedef __attribute__((ext_vector_type(4))) float f32x4;
typedef __attribute__((ext_vector_type(8))) short short8;

#define B_ 32
#define S_ 256
#define E_ 256
#define H_ 512
#define L_ 1024
#define SH_ 131072    // S_*H_ : per-batch stride of out_h / out_att
#define SE_ 65536     // S_*E_ : per-batch stride of y

// ---- workspace layout (float offsets), total 10,340,416 f = 41.36 MB ----
#define OFF_HEB   0           // bf16 h_e: 16,777,216 u16 = 8,388,608 f
#define OFF_WCAT  8388608     // bf16 [2048][1280] = 1,310,720 f
#define OFF_WST   9699328     // bf16 W_s^T [512][512] = 131,072 f
#define OFF_PG    9830400     // fp32 gates [32][2048] = 65,536 f
#define OFF_PSE   9895936     // fp32 [8][32][512] = 131,072 f
#define OFF_PA    10027008    // fp32 [32][16][516] = 264,192 f
#define OFF_HPK   10291200    // u32 packed hi|lo bf16 h [32][512] = 16,384
#define OFF_APK   10307584    // u32 packed att [32][512] = 16,384
#define OFF_C     10323968    // fp32 cell (fallback path only) = 16,384
#define OFF_CNT   10340352    // 64 u32 counters

#define CNT_A     0
#define CNT_B     1
#define CNT_COMB  2
#define CNT16     16          // +b, b<32

__device__ inline u16 f2bf(float x) {
    u32 u = __float_as_uint(x);
    u += 0x7fffu + ((u >> 16) & 1u);
    return (u16)(u >> 16);
}
__device__ inline float bfv(u16 h) { return __uint_as_float((u32)h << 16); }
__device__ inline float bflo(u32 q) { return __uint_as_float(q << 16); }
__device__ inline float bfhi(u32 q) { return __uint_as_float(q & 0xffff0000u); }

// agent-scope (device-coherent, cache-bypassing) accessors
__device__ inline void  stg (float* p, float v) { __hip_atomic_store(p, v, __ATOMIC_RELAXED, __HIP_MEMORY_SCOPE_AGENT); }
__device__ inline float ldgf(const float* p)    { return __hip_atomic_load(p, __ATOMIC_RELAXED, __HIP_MEMORY_SCOPE_AGENT); }
__device__ inline void  stgu(u32* p, u32 v)     { __hip_atomic_store(p, v, __ATOMIC_RELAXED, __HIP_MEMORY_SCOPE_AGENT); }
__device__ inline u32   ldgu(const u32* p)      { return __hip_atomic_load(p, __ATOMIC_RELAXED, __HIP_MEMORY_SCOPE_AGENT); }
__device__ inline void  flag_add(u32* f)        { __hip_atomic_fetch_add(f, 1u, __ATOMIC_RELEASE, __HIP_MEMORY_SCOPE_AGENT); }

__device__ inline void wait_ge(u32* f, u32 tgt, int t) {
    if (t == 0) {
        while (__hip_atomic_load(f, __ATOMIC_RELAXED, __HIP_MEMORY_SCOPE_AGENT) < tgt)
            __builtin_amdgcn_s_sleep(2);
    }
    __syncthreads();
}

__device__ inline void cvt8(const float* __restrict__ src, short8& hi, short8& lo) {
    union { short8 s; u16 h[8]; } H, Lo;
    #pragma unroll
    for (int i = 0; i < 8; ++i) {
        float v = src[i];
        u16 hh = f2bf(v);
        H.h[i] = hh;
        Lo.h[i] = f2bf(v - bfv(hh));
    }
    hi = H.s; lo = Lo.s;
}

__device__ inline void unpk8(const u32* p, short8& hi, short8& lo) {
    union { short8 s; u16 h[8]; } H, Lo;
    #pragma unroll
    for (int i = 0; i < 8; ++i) {
        u32 q = ldgu(p + i);
        H.h[i] = (u16)(q >> 16);
        Lo.h[i] = (u16)(q & 0xffffu);
    }
    hi = H.s; lo = Lo.s;
}

// ---------------- pre: wcat bf16 [2048][1280] = [Wih | Whh]; wst = Ws^T; zero counters ----------------
__global__ void k_cvt(const float* __restrict__ Wih, const float* __restrict__ Whh,
                      const float* __restrict__ Ws,
                      u16* __restrict__ wcat, u16* __restrict__ wst, u32* __restrict__ cnt) {
    if (blockIdx.x == 0 && threadIdx.x < 64) cnt[threadIdx.x] = 0u;
    int idx = blockIdx.x * 256 + threadIdx.x;
    if (idx < 655360) {
        int e4 = idx * 4;
        int r = e4 / 1280, cc = e4 % 1280;
        float4 v;
        if (cc < 768) v = *(const float4*)(Wih + (size_t)r * 768 + cc);
        else          v = *(const float4*)(Whh + (size_t)r * 512 + (cc - 768));
        ushort4 o;
        o.x = f2bf(v.x); o.y = f2bf(v.y); o.z = f2bf(v.z); o.w = f2bf(v.w);
        *(ushort4*)(wcat + e4) = o;
    } else if (idx < 655360 + 262144) {
        int i2 = idx - 655360;
        int j = i2 >> 9, r = i2 & 511;
        wst[i2] = f2bf(Ws[(size_t)r * 512 + j]);
    }
}

// ---------------- h_e = encoder_h @ W_h.T + b_h (bf16 out) — proven R2 kernel ----------------
__global__ __launch_bounds__(256) void k_he(const float* __restrict__ A,
                                            const float* __restrict__ W,
                                            const float* __restrict__ bias,
                                            u16* __restrict__ C) {
    __shared__ float As[64][36];
    __shared__ float Bs[64][37];
    const int m0 = blockIdx.y * 64;
    const int n0 = blockIdx.x * 64;
    const int tid = threadIdx.x;
    const int tx = tid & 15, ty = tid >> 4;
    float acc[4][4] = {};
    for (int kk = 0; kk < 512; kk += 32) {
        #pragma unroll
        for (int i = 0; i < 2; ++i) {
            int idx = tid + i * 256;
            int r = idx >> 3, c4 = (idx & 7) << 2;
            float4 va = *(const float4*)(A + (size_t)(m0 + r) * 512 + kk + c4);
            *(float4*)&As[r][c4] = va;
            float4 vb = *(const float4*)(W + (size_t)(n0 + r) * 512 + kk + c4);
            Bs[r][c4 + 0] = vb.x; Bs[r][c4 + 1] = vb.y;
            Bs[r][c4 + 2] = vb.z; Bs[r][c4 + 3] = vb.w;
        }
        __syncthreads();
        #pragma unroll
        for (int k2 = 0; k2 < 32; ++k2) {
            float a[4], b[4];
            #pragma unroll
            for (int i = 0; i < 4; ++i) a[i] = As[ty * 4 + i][k2];
            #pragma unroll
            for (int j = 0; j < 4; ++j) b[j] = Bs[tx * 4 + j][k2];
            #pragma unroll
            for (int i = 0; i < 4; ++i)
                #pragma unroll
                for (int j = 0; j < 4; ++j) acc[i][j] += a[i] * b[j];
        }
        __syncthreads();
    }
    float bj[4];
    #pragma unroll
    for (int j = 0; j < 4; ++j) bj[j] = bias[n0 + tx * 4 + j];
    #pragma unroll
    for (int i = 0; i < 4; ++i) {
        ushort4 r4;
        r4.x = f2bf(acc[i][0] + bj[0]); r4.y = f2bf(acc[i][1] + bj[1]);
        r4.z = f2bf(acc[i][2] + bj[2]); r4.w = f2bf(acc[i][3] + bj[3]);
        *(ushort4*)(C + (size_t)(m0 + ty * 4 + i) * 512 + n0 + tx * 4) = r4;
    }
}

// ---------------- shared phases ----------------
struct P {
    const float* y;
    const u16*   heb;
    const u16*   wcat;
    const u16*   wst;
    const float* bih;
    const float* bhh;
    const float* bs;
    float*       pg;
    float*       pse;
    float*       pa;
    u32*         hpk;
    u32*         apk;
    float*       c;
    u32*         cnt;
    float*       out_h;
    float*       out_att;
};

#define MFMA(a, b, c) __builtin_amdgcn_mfma_f32_16x16x32_bf16(a, b, c, 0, 0, 0)

// gates (full K), 32 blocks. pg[b][2048] = wcat @ [y_t; att; h]  (pre-bias)
__device__ void phaseA(const P& p, int ts, int bid, int t) {
    if (bid >= 32) return;
    if (ts > 0) wait_ge(p.cnt + CNT_COMB, 32u * (u32)ts, t);
    const int wv = t >> 6, lane = t & 63;
    const int r0 = bid * 64 + wv * 16;
    const int row = lane & 15, q = lane >> 4, ksl = q * 8;
    const u16* wrow = p.wcat + (size_t)(r0 + row) * 1280 + ksl;
    f32x4 acc0 = {0.f, 0.f, 0.f, 0.f}, acc1 = {0.f, 0.f, 0.f, 0.f};
    union { uint4 u; short8 s; } A;
    short8 B0h, B0l, B1h, B1l;
    #pragma unroll
    for (int kc = 0; kc < 256; kc += 32) {   // y region (always)
        A.u = *(const uint4*)(wrow + kc);
        cvt8(p.y + (size_t)row * SE_ + (size_t)ts * 256 + kc + ksl, B0h, B0l);
        cvt8(p.y + (size_t)(16 + row) * SE_ + (size_t)ts * 256 + kc + ksl, B1h, B1l);
        acc0 = MFMA(A.s, B0h, acc0); acc0 = MFMA(A.s, B0l, acc0);
        acc1 = MFMA(A.s, B1h, acc1); acc1 = MFMA(A.s, B1l, acc1);
    }
    if (ts > 0) {
        #pragma unroll 4
        for (int kc = 256; kc < 768; kc += 32) {   // att region
            A.u = *(const uint4*)(wrow + kc);
            unpk8(p.apk + (size_t)row * 512 + (kc - 256) + ksl, B0h, B0l);
            unpk8(p.apk + (size_t)(16 + row) * 512 + (kc - 256) + ksl, B1h, B1l);
            acc0 = MFMA(A.s, B0h, acc0); acc0 = MFMA(A.s, B0l, acc0);
            acc1 = MFMA(A.s, B1h, acc1); acc1 = MFMA(A.s, B1l, acc1);
        }
        #pragma unroll 4
        for (int kc = 768; kc < 1280; kc += 32) {  // h region
            A.u = *(const uint4*)(wrow + kc);
            unpk8(p.hpk + (size_t)row * 512 + (kc - 768) + ksl, B0h, B0l);
            unpk8(p.hpk + (size_t)(16 + row) * 512 + (kc - 768) + ksl, B1h, B1l);
            acc0 = MFMA(A.s, B0h, acc0); acc0 = MFMA(A.s, B0l, acc0);
            acc1 = MFMA(A.s, B1h, acc1); acc1 = MFMA(A.s, B1l, acc1);
        }
    }
    // D layout: col = lane&15 (batch), rows = q*4+i (gate row)
    #pragma unroll
    for (int i = 0; i < 4; ++i) {
        stg(p.pg + (size_t)row * 2048 + r0 + q * 4 + i, acc0[i]);
        stg(p.pg + (size_t)(16 + row) * 2048 + r0 + q * 4 + i, acc1[i]);
    }
    __syncthreads();
    if (t == 0) flag_add(p.cnt + CNT_A);
}

// LSTM pointwise + s_e partials, 128 blocks = 8 dtl(64 d) x 16 bgl(2 b)
template<bool PER>
__device__ void phaseB(const P& p, int ts, int bid, int t, float& creg) {
    if (bid >= 128) return;
    wait_ge(p.cnt + CNT_A, 32u * (u32)(ts + 1), t);
    __shared__ float hloc[64][2];
    const int dtl = bid >> 4, bgl = bid & 15;
    if (t < 128) {
        const int d = dtl * 64 + (t & 63);
        const int b = bgl * 2 + (t >> 6);
        float g0 = p.bih[d]        + p.bhh[d]        + ldgf(p.pg + (size_t)b * 2048 + d);
        float g1 = p.bih[512 + d]  + p.bhh[512 + d]  + ldgf(p.pg + (size_t)b * 2048 + 512 + d);
        float g2 = p.bih[1024 + d] + p.bhh[1024 + d] + ldgf(p.pg + (size_t)b * 2048 + 1024 + d);
        float g3 = p.bih[1536 + d] + p.bhh[1536 + d] + ldgf(p.pg + (size_t)b * 2048 + 1536 + d);
        float si = 1.f / (1.f + __expf(-g0));
        float sf = 1.f / (1.f + __expf(-g1));
        float so = 1.f / (1.f + __expf(-g3));
        float cprev = PER ? creg : ((ts == 0) ? 0.f : p.c[b * 512 + d]);
        float cc = sf * cprev + si * tanhf(g2);
        if (PER) creg = cc; else p.c[b * 512 + d] = cc;
        float hv = so * tanhf(cc);
        stg(p.out_h + (size_t)b * SH_ + (size_t)ts * 512 + d, hv);
        u16 hi = f2bf(hv), lo = f2bf(hv - bfv(hi));
        stgu(p.hpk + b * 512 + d, ((u32)hi << 16) | (u32)lo);
        hloc[t & 63][t >> 6] = hv;
    }
    __syncthreads();
    // pse[dtl][b][r] = sum_{j in 64-d tile} Ws[r][j] * h[b][j]
    float a0[2] = {0.f, 0.f}, a1[2] = {0.f, 0.f};
    #pragma unroll 8
    for (int j = 0; j < 64; ++j) {
        const u16* wr = p.wst + (size_t)(dtl * 64 + j) * 512 + t;
        float w0 = bfv(wr[0]), w1 = bfv(wr[256]);
        float h0 = hloc[j][0], h1 = hloc[j][1];
        a0[0] += w0 * h0; a0[1] += w0 * h1;
        a1[0] += w1 * h0; a1[1] += w1 * h1;
    }
    #pragma unroll
    for (int bb = 0; bb < 2; ++bb) {
        const int b = bgl * 2 + bb;
        stg(p.pse + (size_t)dtl * 16384 + (size_t)b * 512 + t,       a0[bb]);
        stg(p.pse + (size_t)dtl * 16384 + (size_t)b * 512 + t + 256, a1[bb]);
    }
    __syncthreads();
    if (t == 0) flag_add(p.cnt + CNT_B);
}

// attention, 512 blocks = 32 b x 16 ch; ch==0 block combines
__device__ void phaseC(const P& p, int ts, int bid, int t) {
    wait_ge(p.cnt + CNT_B, 128u * (u32)(ts + 1), t);
    __shared__ float se[512];
    __shared__ float part[64][5];
    __shared__ float pl[64];
    __shared__ float sm16[16], sz16[16], swt[16];
    __shared__ float mzm, mzz, szt;
    const int b = bid >> 4, ch = bid & 15, l0 = ch * 64;
    #pragma unroll
    for (int i = 0; i < 2; ++i) {
        int r = t + i * 256;
        float v = p.bs[r];
        #pragma unroll
        for (int dd = 0; dd < 8; ++dd)
            v += ldgf(p.pse + (size_t)dd * 16384 + (size_t)b * 512 + r);
        se[r] = v;
    }
    __syncthreads();
    {   // e_l partials: (l = t&63) x (w = t>>6 covers 128 h)
        const int l = t & 63, w = t >> 6;
        const u16* hrow = p.heb + ((size_t)b * L_ + l0 + l) * H_ + w * 128;
        const float* sew = &se[w * 128];
        float dp = 0.f;
        #pragma unroll
        for (int kc = 0; kc < 128; kc += 8) {
            uint4 qq = *(const uint4*)(hrow + kc);
            dp += sew[kc + 0] * bflo(qq.x) + sew[kc + 1] * bfhi(qq.x)
                + sew[kc + 2] * bflo(qq.y) + sew[kc + 3] * bfhi(qq.y)
                + sew[kc + 4] * bflo(qq.z) + sew[kc + 5] * bfhi(qq.z)
                + sew[kc + 6] * bflo(qq.w) + sew[kc + 7] * bfhi(qq.w);
        }
        part[l][w] = dp;
    }
    __syncthreads();
    if (t < 64) {
        float e = part[t][0] + part[t][1] + part[t][2] + part[t][3];
        float m = e;
        #pragma unroll
        for (int off = 1; off < 64; off <<= 1) m = fmaxf(m, __shfl_xor(m, off));
        float pv = __expf(e - m);
        float Z = pv;
        #pragma unroll
        for (int off = 1; off < 64; off <<= 1) Z += __shfl_xor(Z, off);
        pl[t] = pv;
        if (t == 0) { mzm = m; mzz = Z; }
    }
    __syncthreads();
    {   // ctx partials: thread covers 2 h over 64 l (tile L2-hot)
        float c0 = 0.f, c1 = 0.f;
        const u16* base2 = p.heb + ((size_t)b * L_ + l0) * H_ + t * 2;
        #pragma unroll 8
        for (int j = 0; j < 64; ++j) {
            u32 qq = *(const u32*)(base2 + (size_t)j * 512);
            float pv = pl[j];
            c0 += pv * bflo(qq); c1 += pv * bfhi(qq);
        }
        float* dst = p.pa + ((size_t)b * 16 + ch) * 516;
        stg(dst + 2 * t, c0);
        stg(dst + 2 * t + 1, c1);
        if (t == 0) { stg(dst + 512, mzm); stg(dst + 513, mzz); }
    }
    __syncthreads();
    if (t == 0) flag_add(p.cnt + CNT16 + b);
    if (ch == 0) {  // combiner
        wait_ge(p.cnt + CNT16 + b, 16u * (u32)(ts + 1), t);
        if (t < 16) {
            sm16[t] = ldgf(p.pa + ((size_t)b * 16 + t) * 516 + 512);
            sz16[t] = ldgf(p.pa + ((size_t)b * 16 + t) * 516 + 513);
        }
        __syncthreads();
        if (t == 0) {
            float M = sm16[0];
            #pragma unroll
            for (int i2 = 1; i2 < 16; ++i2) M = fmaxf(M, sm16[i2]);
            float Zt = 0.f;
            #pragma unroll
            for (int i2 = 0; i2 < 16; ++i2) {
                float wv = __expf(sm16[i2] - M);
                swt[i2] = wv;
                Zt += wv * sz16[i2];
            }
            szt = Zt;
        }
        __syncthreads();
        const float inv = 1.f / szt;
        float A0 = 0.f, A1 = 0.f;
        #pragma unroll
        for (int i2 = 0; i2 < 16; ++i2) {
            const float* pp = p.pa + ((size_t)b * 16 + i2) * 516 + 2 * t;
            float wv = swt[i2];
            A0 += wv * ldgf(pp); A1 += wv * ldgf(pp + 1);
        }
        A0 *= inv; A1 *= inv;
        stg(p.out_att + (size_t)b * SH_ + (size_t)ts * 512 + 2 * t, A0);
        stg(p.out_att + (size_t)b * SH_ + (size_t)ts * 512 + 2 * t + 1, A1);
        u16 h0 = f2bf(A0), l0_ = f2bf(A0 - bfv(h0));
        u16 h1 = f2bf(A1), l1_ = f2bf(A1 - bfv(h1));
        stgu(p.apk + b * 512 + 2 * t,     ((u32)h0 << 16) | (u32)l0_);
        stgu(p.apk + b * 512 + 2 * t + 1, ((u32)h1 << 16) | (u32)l1_);
        __syncthreads();
        if (t == 0) flag_add(p.cnt + CNT_COMB);
    }
}

// ---------------- driver 1: persistent (no grid.sync — flag-based) ----------------
__global__ __launch_bounds__(256, 2) void k_steps(P p) {
    float creg = 0.f;
    for (int ts = 0; ts < S_; ++ts) {
        phaseA(p, ts, blockIdx.x, threadIdx.x);
        phaseB<true>(p, ts, blockIdx.x, threadIdx.x, creg);
        phaseC(p, ts, blockIdx.x, threadIdx.x);
    }
}

// ---------------- driver 2: fallback multi-launch (same phases; waits satisfied at entry) ----------------
__global__ __launch_bounds__(256) void k_pA(P p, int ts) { phaseA(p, ts, blockIdx.x, threadIdx.x); }
__global__ __launch_bounds__(256) void k_pB(P p, int ts) {
    float dummy = 0.f;
    phaseB<false>(p, ts, blockIdx.x, threadIdx.x, dummy);
}
__global__ __launch_bounds__(256) void k_pC(P p, int ts) { phaseC(p, ts, blockIdx.x, threadIdx.x); }

extern "C" void kernel_launch(void* const* d_in, const int* in_sizes, int n_in,
                              void* d_out, int out_size, void* d_ws, size_t ws_size,
                              hipStream_t stream) {
    const float* y   = (const float*)d_in[0];
    const float* enc = (const float*)d_in[1];
    const float* Wih = (const float*)d_in[2];
    const float* bih = (const float*)d_in[3];
    const float* Whh = (const float*)d_in[4];
    const float* bhh = (const float*)d_in[5];
    const float* Ws_ = (const float*)d_in[6];
    const float* bs  = (const float*)d_in[7];
    const float* Wh  = (const float*)d_in[8];
    const float* bh  = (const float*)d_in[9];

    float* ws = (float*)d_ws;
    u16* heb  = (u16*)(ws + OFF_HEB);
    u16* wcat = (u16*)(ws + OFF_WCAT);
    u16* wst  = (u16*)(ws + OFF_WST);
    u32* cnt  = (u32*)(ws + OFF_CNT);
    float* out_h   = (float*)d_out;
    float* out_att = out_h + (size_t)B_ * S_ * H_;

    k_cvt<<<3584, 256, 0, stream>>>(Wih, Whh, Ws_, wcat, wst, cnt);
    k_he<<<dim3(8, 512), 256, 0, stream>>>(enc, Wh, bh, heb);

    P p;
    p.y = y; p.heb = heb; p.wcat = wcat; p.wst = wst;
    p.bih = bih; p.bhh = bhh; p.bs = bs;
    p.pg  = ws + OFF_PG;
    p.pse = ws + OFF_PSE;
    p.pa  = ws + OFF_PA;
    p.hpk = (u32*)(ws + OFF_HPK);
    p.apk = (u32*)(ws + OFF_APK);
    p.c   = ws + OFF_C;
    p.cnt = cnt;
    p.out_h = out_h; p.out_att = out_att;

    void* args[] = { &p };
    hipError_t err = hipLaunchCooperativeKernel((const void*)k_steps,
                                                dim3(512), dim3(256), args, 0, stream);
    if (err != hipSuccess) {
        (void)hipGetLastError();
        for (int ts = 0; ts < S_; ++ts) {
            k_pA<<<32, 256, 0, stream>>>(p, ts);
            k_pB<<<128, 256, 0, stream>>>(p, ts);
            k_pC<<<512, 256, 0, stream>>>(p, ts);
        }
    }
}